// Round 13
// baseline (105.628 us; speedup 1.0000x reference)
//
#include <hip/hip_runtime.h>

// Focus: space-to-depth(2x2) + 1x1 conv (12 -> 64) + BatchNorm(inference) + SiLU
// x: [16,3,640,640] f32, W: [64,12] f32, out: [16,64,320,320] f32
// R13: last factorial cell at {TPB=64, unroll 4}: NT LOADS + NORMAL STORES.
//   ledger: normal/nt = 92.1 | nt/nt = 104.8 | normal/normal = 109.5 | nt/normal = ?
//   Theory: the two penalties interact through L2 — normal stores lost because
//   they thrash against read allocations; with nt loads L2 is store-exclusive
//   (= fill kernel's regime, 6.9 TB/s). Win => new branch; loss => R6 roofline.

typedef float f32x4 __attribute__((ext_vector_type(4)));
typedef float f32x2 __attribute__((ext_vector_type(2)));

namespace {
constexpr int B    = 16;
constexpr int CIN  = 3;
constexpr int CH   = 640;
constexpr int CW   = 640;
constexpr int COUT = 64;
constexpr int OH   = 320;
constexpr int OW   = 320;
constexpr float EPS = 1e-5f;

constexpr int TPB = 64;
constexpr int QPR = OW / 4;            // 80 quads (4 out-cols) per row
constexpr int QPI = OH * QPR;          // 25600 per image
constexpr int TOTAL_Q = B * QPI;       // 409600
constexpr int GRID = TOTAL_Q / TPB;    // 6400 blocks, exact (25 per CU)
}

__global__ __launch_bounds__(TPB) void focus_fused(
    const float* __restrict__ x, const float* __restrict__ W,
    const float* __restrict__ gamma, const float* __restrict__ beta,
    const float* __restrict__ rmean, const float* __restrict__ rvar,
    float* __restrict__ out)
{
    // Pre-splatted BN scale/shift: {sc,sc,sh,sh} per output channel (1 KB LDS).
    __shared__ __attribute__((aligned(16))) f32x4 ScSh[COUT];

    const int tid = threadIdx.x;
    {
        float sc = gamma[tid] * rsqrtf(rvar[tid] + EPS);
        float sh = beta[tid] - rmean[tid] * sc;
        f32x4 t; t.x = sc; t.y = sc; t.z = sh; t.w = sh;
        ScSh[tid] = t;
    }
    __syncthreads();   // single wave: compiles to waitcnt only

    // Each thread: 4 consecutive output columns (one quad) of one output row.
    const int q   = blockIdx.x * TPB + tid;
    const int b   = q / QPI;
    const int rem = q - b * QPI;
    const int h   = rem / QPR;
    const int u   = rem - h * QPR;
    const float* xb = x + (((long)b * CIN) * CH + 2 * h) * (long)CW + 8 * u;

    // Deinterleave input cols into even {0,2,4,6} / odd {1,3,5,7} vectors.
    f32x4 ve[CIN][2], vo[CIN][2];
#pragma unroll
    for (int c = 0; c < CIN; ++c) {
#pragma unroll
        for (int r = 0; r < 2; ++r) {
            const float* p = xb + ((long)c * CH + r) * CW;
            f32x4 f0 = __builtin_nontemporal_load(reinterpret_cast<const f32x4*>(p));
            f32x4 f1 = __builtin_nontemporal_load(reinterpret_cast<const f32x4*>(p) + 1);
            f32x4 e; e.x = f0.x; e.y = f0.z; e.z = f1.x; e.w = f1.z;
            f32x4 d; d.x = f0.y; d.y = f0.w; d.z = f1.y; d.w = f1.w;
            ve[c][r] = e; vo[c][r] = d;
        }
    }

    float* ob = out + ((long)b * COUT) * (OH * OW) + h * OW + 4 * u;

    // concat order: weight idx k = s*3+c, s: 0=(r0,even c) 1=(r1,even c)
    //                                       2=(r0,odd c)  3=(r1,odd c)
#pragma unroll 4
    for (int o = 0; o < COUT; ++o) {
        const float* wrow = W + o * 12;   // uniform index -> scalar loads

        // 4 independent packed accumulator chains (2 outputs each).
        f32x2 aLe = {0.f, 0.f}, aLo = {0.f, 0.f};
        f32x2 aHe = {0.f, 0.f}, aHo = {0.f, 0.f};
#pragma unroll
        for (int c = 0; c < CIN; ++c) {
#pragma unroll
            for (int r = 0; r < 2; ++r) {
                const float we = wrow[r * 3 + c];      // even-col weight (SGPR)
                const float wd = wrow[6 + r * 3 + c];  // odd-col weight (SGPR)
                f32x2 we2; we2.x = we; we2.y = we;
                f32x2 wd2; wd2.x = wd; wd2.y = wd;
                aLe = __builtin_elementwise_fma(we2, ve[c][r].xy, aLe);
                aHe = __builtin_elementwise_fma(we2, ve[c][r].zw, aHe);
                aLo = __builtin_elementwise_fma(wd2, vo[c][r].xy, aLo);
                aHo = __builtin_elementwise_fma(wd2, vo[c][r].zw, aHo);
            }
        }
        const f32x4 ss = ScSh[o];
        f32x2 sc2 = ss.xy, sh2 = ss.zw;
        f32x2 aL = aLe + aLo, aH = aHe + aHo;
        aL = __builtin_elementwise_fma(aL, sc2, sh2);
        aH = __builtin_elementwise_fma(aH, sc2, sh2);

        // SiLU: y = a * rcp(1 + exp2(-a*log2e)); packed glue, scalar trans.
        f32x2 tL = aL * -1.44269504088896f;
        f32x2 tH = aH * -1.44269504088896f;
        f32x2 eL; eL.x = __builtin_amdgcn_exp2f(tL.x); eL.y = __builtin_amdgcn_exp2f(tL.y);
        f32x2 eH; eH.x = __builtin_amdgcn_exp2f(tH.x); eH.y = __builtin_amdgcn_exp2f(tH.y);
        f32x2 dL = eL + 1.0f, dH = eH + 1.0f;
        f32x2 rL; rL.x = __builtin_amdgcn_rcpf(dL.x); rL.y = __builtin_amdgcn_rcpf(dL.y);
        f32x2 rH; rH.x = __builtin_amdgcn_rcpf(dH.x); rH.y = __builtin_amdgcn_rcpf(dH.y);
        f32x2 oL = aL * rL, oH = aH * rH;

        f32x4 rs; rs.x = oL.x; rs.y = oL.y; rs.z = oH.x; rs.w = oH.y;
        *reinterpret_cast<f32x4*>(ob + o * (OH * OW)) = rs;   // normal store
    }
}

extern "C" void kernel_launch(void* const* d_in, const int* in_sizes, int n_in,
                              void* d_out, int out_size, void* d_ws, size_t ws_size,
                              hipStream_t stream) {
    const float* x     = (const float*)d_in[0];
    const float* W     = (const float*)d_in[1];
    const float* gamma = (const float*)d_in[2];
    const float* beta  = (const float*)d_in[3];
    const float* rmean = (const float*)d_in[4];
    const float* rvar  = (const float*)d_in[5];
    float* out = (float*)d_out;
    focus_fused<<<GRID, TPB, 0, stream>>>(x, W, gamma, beta, rmean, rvar, out);
}

// Round 14
// 91.663 us; speedup vs baseline: 1.1524x; 1.1524x over previous
//
#include <hip/hip_runtime.h>

// Focus: space-to-depth(2x2) + 1x1 conv (12 -> 64) + BatchNorm(inference) + SiLU
// x: [16,3,640,640] f32, W: [64,12] f32, out: [16,64,320,320] f32
// FINAL (== R6/R12, 92.1-92.3 us, 5.0-5.4 TB/s effective = 80-86% of copy BW):
//   TPB=64 (6400 single-wave blocks, 25/CU), NORMAL loads, NONTEMPORAL stores,
//   o-loop unroll 4, packed f32x2 math, SGPR weights, BN post-accumulation,
//   fast SiLU via v_exp_f32 + v_rcp_f32.
// Cache-policy factorial (all measured): normal-ld/nt-st 92.1 | nt/nt 104.8 |
//   normal/normal 109.5 | nt/normal 105.6. Stagger +2.6. 2KB-run variants
//   spill-blocked (compiler pins 60 VGPR at TPB=64 regardless of launch_bounds).

typedef float f32x4 __attribute__((ext_vector_type(4)));
typedef float f32x2 __attribute__((ext_vector_type(2)));

namespace {
constexpr int B    = 16;
constexpr int CIN  = 3;
constexpr int CH   = 640;
constexpr int CW   = 640;
constexpr int COUT = 64;
constexpr int OH   = 320;
constexpr int OW   = 320;
constexpr float EPS = 1e-5f;

constexpr int TPB = 64;
constexpr int QPR = OW / 4;            // 80 quads (4 out-cols) per row
constexpr int QPI = OH * QPR;          // 25600 per image
constexpr int TOTAL_Q = B * QPI;       // 409600
constexpr int GRID = TOTAL_Q / TPB;    // 6400 blocks, exact (25 per CU)
}

__global__ __launch_bounds__(TPB) void focus_fused(
    const float* __restrict__ x, const float* __restrict__ W,
    const float* __restrict__ gamma, const float* __restrict__ beta,
    const float* __restrict__ rmean, const float* __restrict__ rvar,
    float* __restrict__ out)
{
    // Pre-splatted BN scale/shift: {sc,sc,sh,sh} per output channel (1 KB LDS).
    __shared__ __attribute__((aligned(16))) f32x4 ScSh[COUT];

    const int tid = threadIdx.x;
    {
        float sc = gamma[tid] * rsqrtf(rvar[tid] + EPS);
        float sh = beta[tid] - rmean[tid] * sc;
        f32x4 t; t.x = sc; t.y = sc; t.z = sh; t.w = sh;
        ScSh[tid] = t;
    }
    __syncthreads();   // single wave: compiles to waitcnt only

    // Each thread: 4 consecutive output columns (one quad) of one output row.
    const int q   = blockIdx.x * TPB + tid;
    const int b   = q / QPI;
    const int rem = q - b * QPI;
    const int h   = rem / QPR;
    const int u   = rem - h * QPR;
    const float* xb = x + (((long)b * CIN) * CH + 2 * h) * (long)CW + 8 * u;

    // Deinterleave input cols into even {0,2,4,6} / odd {1,3,5,7} vectors.
    f32x4 ve[CIN][2], vo[CIN][2];
#pragma unroll
    for (int c = 0; c < CIN; ++c) {
#pragma unroll
        for (int r = 0; r < 2; ++r) {
            const float* p = xb + ((long)c * CH + r) * CW;
            f32x4 f0 = *reinterpret_cast<const f32x4*>(p);
            f32x4 f1 = *(reinterpret_cast<const f32x4*>(p) + 1);
            f32x4 e; e.x = f0.x; e.y = f0.z; e.z = f1.x; e.w = f1.z;
            f32x4 d; d.x = f0.y; d.y = f0.w; d.z = f1.y; d.w = f1.w;
            ve[c][r] = e; vo[c][r] = d;
        }
    }

    float* ob = out + ((long)b * COUT) * (OH * OW) + h * OW + 4 * u;

    // concat order: weight idx k = s*3+c, s: 0=(r0,even c) 1=(r1,even c)
    //                                       2=(r0,odd c)  3=(r1,odd c)
#pragma unroll 4
    for (int o = 0; o < COUT; ++o) {
        const float* wrow = W + o * 12;   // uniform index -> scalar loads

        // 4 independent packed accumulator chains (2 outputs each).
        f32x2 aLe = {0.f, 0.f}, aLo = {0.f, 0.f};
        f32x2 aHe = {0.f, 0.f}, aHo = {0.f, 0.f};
#pragma unroll
        for (int c = 0; c < CIN; ++c) {
#pragma unroll
            for (int r = 0; r < 2; ++r) {
                const float we = wrow[r * 3 + c];      // even-col weight (SGPR)
                const float wd = wrow[6 + r * 3 + c];  // odd-col weight (SGPR)
                f32x2 we2; we2.x = we; we2.y = we;
                f32x2 wd2; wd2.x = wd; wd2.y = wd;
                aLe = __builtin_elementwise_fma(we2, ve[c][r].xy, aLe);
                aHe = __builtin_elementwise_fma(we2, ve[c][r].zw, aHe);
                aLo = __builtin_elementwise_fma(wd2, vo[c][r].xy, aLo);
                aHo = __builtin_elementwise_fma(wd2, vo[c][r].zw, aHo);
            }
        }
        const f32x4 ss = ScSh[o];
        f32x2 sc2 = ss.xy, sh2 = ss.zw;
        f32x2 aL = aLe + aLo, aH = aHe + aHo;
        aL = __builtin_elementwise_fma(aL, sc2, sh2);
        aH = __builtin_elementwise_fma(aH, sc2, sh2);

        // SiLU: y = a * rcp(1 + exp2(-a*log2e)); packed glue, scalar trans.
        f32x2 tL = aL * -1.44269504088896f;
        f32x2 tH = aH * -1.44269504088896f;
        f32x2 eL; eL.x = __builtin_amdgcn_exp2f(tL.x); eL.y = __builtin_amdgcn_exp2f(tL.y);
        f32x2 eH; eH.x = __builtin_amdgcn_exp2f(tH.x); eH.y = __builtin_amdgcn_exp2f(tH.y);
        f32x2 dL = eL + 1.0f, dH = eH + 1.0f;
        f32x2 rL; rL.x = __builtin_amdgcn_rcpf(dL.x); rL.y = __builtin_amdgcn_rcpf(dL.y);
        f32x2 rH; rH.x = __builtin_amdgcn_rcpf(dH.x); rH.y = __builtin_amdgcn_rcpf(dH.y);
        f32x2 oL = aL * rL, oH = aH * rH;

        f32x4 rs; rs.x = oL.x; rs.y = oL.y; rs.z = oH.x; rs.w = oH.y;
        __builtin_nontemporal_store(rs, reinterpret_cast<f32x4*>(ob + o * (OH * OW)));
    }
}

extern "C" void kernel_launch(void* const* d_in, const int* in_sizes, int n_in,
                              void* d_out, int out_size, void* d_ws, size_t ws_size,
                              hipStream_t stream) {
    const float* x     = (const float*)d_in[0];
    const float* W     = (const float*)d_in[1];
    const float* gamma = (const float*)d_in[2];
    const float* beta  = (const float*)d_in[3];
    const float* rmean = (const float*)d_in[4];
    const float* rvar  = (const float*)d_in[5];
    float* out = (float*)d_out;
    focus_fused<<<GRID, TPB, 0, stream>>>(x, W, gamma, beta, rmean, rvar, out);
}